// Round 4
// baseline (7103.043 us; speedup 1.0000x reference)
//
#include <hip/hip_runtime.h>

constexpr int D = 1024;   // d_model
constexpr int S = 1024;   // seq len
constexpr int NB = 4;     // batch
constexpr int NH = 16;    // heads
constexpr int DK = 64;    // head dim
constexpr float THRESH = 0.019f;
constexpr float NEG_INF = -1e9f;
constexpr int ROWS = 8;   // q-rows per attention block

__device__ __forceinline__ float wave_max(float v) {
#pragma unroll
    for (int off = 32; off >= 1; off >>= 1)
        v = fmaxf(v, __shfl_xor(v, off, 64));
    return v;
}
__device__ __forceinline__ float wave_sum(float v) {
#pragma unroll
    for (int off = 32; off >= 1; off >>= 1)
        v += __shfl_xor(v, off, 64);
    return v;
}

// Y[m][n] = sum_k X[m][k] * W[n][k] + bias[n]. 128x128 tile, 8x8 micro-tile.
// q,v written head-split [B,H,S,DK]; k written TRANSPOSED [B,H,DK,S].
__global__ __launch_bounds__(256) void proj_kernel(
    const float* __restrict__ Qi, const float* __restrict__ Ki, const float* __restrict__ Vi,
    const float* __restrict__ Wq, const float* __restrict__ bq,
    const float* __restrict__ Wk, const float* __restrict__ bk,
    const float* __restrict__ Wv, const float* __restrict__ bv,
    float* __restrict__ qo, float* __restrict__ ko, float* __restrict__ vo)
{
    const int pz = blockIdx.z;
    const float* __restrict__ X    = (pz == 0) ? Qi : (pz == 1) ? Ki : Vi;
    const float* __restrict__ W    = (pz == 0) ? Wq : (pz == 1) ? Wk : Wv;
    const float* __restrict__ bias = (pz == 0) ? bq : (pz == 1) ? bk : bv;
    float* __restrict__ out        = (pz == 0) ? qo : (pz == 1) ? ko : vo;

    __shared__ __align__(16) float As[16][132];   // [k][m] transposed
    __shared__ __align__(16) float Bs[16][132];   // [k][n] transposed

    const int t  = threadIdx.x;
    const int tx = t & 15;
    const int ty = t >> 4;
    const int m0 = blockIdx.y * 128;
    const int n0 = blockIdx.x * 128;
    const int srow = t >> 1;           // staging row 0..127
    const int sk   = 8 * (t & 1);      // staging k offset 0 or 8

    float acc[2][2][4][4] = {};        // [im][in][i][j]

    for (int k0 = 0; k0 < D; k0 += 16) {
        float4 xa = *(const float4*)&X[(size_t)(m0 + srow) * D + k0 + sk];
        float4 xb = *(const float4*)&X[(size_t)(m0 + srow) * D + k0 + sk + 4];
        float4 wa = *(const float4*)&W[(size_t)(n0 + srow) * D + k0 + sk];
        float4 wb = *(const float4*)&W[(size_t)(n0 + srow) * D + k0 + sk + 4];
        As[sk + 0][srow] = xa.x; As[sk + 1][srow] = xa.y; As[sk + 2][srow] = xa.z; As[sk + 3][srow] = xa.w;
        As[sk + 4][srow] = xb.x; As[sk + 5][srow] = xb.y; As[sk + 6][srow] = xb.z; As[sk + 7][srow] = xb.w;
        Bs[sk + 0][srow] = wa.x; Bs[sk + 1][srow] = wa.y; Bs[sk + 2][srow] = wa.z; Bs[sk + 3][srow] = wa.w;
        Bs[sk + 4][srow] = wb.x; Bs[sk + 5][srow] = wb.y; Bs[sk + 6][srow] = wb.z; Bs[sk + 7][srow] = wb.w;
        __syncthreads();
#pragma unroll
        for (int kk = 0; kk < 16; ++kk) {
            float4 a0 = *(const float4*)&As[kk][ty * 4];
            float4 a1 = *(const float4*)&As[kk][ty * 4 + 64];
            float4 b0 = *(const float4*)&Bs[kk][tx * 4];
            float4 b1 = *(const float4*)&Bs[kk][tx * 4 + 64];
            float am[2][4] = {{a0.x, a0.y, a0.z, a0.w}, {a1.x, a1.y, a1.z, a1.w}};
            float bn[2][4] = {{b0.x, b0.y, b0.z, b0.w}, {b1.x, b1.y, b1.z, b1.w}};
#pragma unroll
            for (int im = 0; im < 2; ++im)
#pragma unroll
                for (int in = 0; in < 2; ++in)
#pragma unroll
                    for (int i = 0; i < 4; ++i)
#pragma unroll
                        for (int j = 0; j < 4; ++j)
                            acc[im][in][i][j] += am[im][i] * bn[in][j];
        }
        __syncthreads();
    }

    const int bb2 = m0 >> 10;              // batch (m0 multiple of 128)
    if (pz == 1) {
        // kT[((b*NH+h)*DK + d)*S + s], f4 along s
#pragma unroll
        for (int im = 0; im < 2; ++im) {
            const int s0 = (m0 & 1023) + ty * 4 + 64 * im;
#pragma unroll
            for (int in = 0; in < 2; ++in) {
#pragma unroll
                for (int j = 0; j < 4; ++j) {
                    const int n = n0 + tx * 4 + 64 * in + j;
                    const int h = n >> 6, d = n & 63;
                    const float bj = bias[n];
                    float4 wv = make_float4(acc[im][in][0][j] + bj, acc[im][in][1][j] + bj,
                                            acc[im][in][2][j] + bj, acc[im][in][3][j] + bj);
                    *(float4*)&out[(((size_t)bb2 * NH + h) * DK + d) * S + s0] = wv;
                }
            }
        }
    } else {
#pragma unroll
        for (int im = 0; im < 2; ++im)
#pragma unroll
            for (int i = 0; i < 4; ++i) {
                const int m  = m0 + ty * 4 + 64 * im + i;
                const int sr = m & 1023;
#pragma unroll
                for (int in = 0; in < 2; ++in) {
                    const int n = n0 + tx * 4 + 64 * in;
                    const int h = n >> 6, d = n & 63;
                    const float4 bj = *(const float4*)&bias[n];
                    float4 wv = make_float4(acc[im][in][i][0] + bj.x, acc[im][in][i][1] + bj.y,
                                            acc[im][in][i][2] + bj.z, acc[im][in][i][3] + bj.w);
                    *(float4*)&out[(((size_t)bb2 * NH + h) * S + sr) * DK + d] = wv;
                }
            }
    }
}

// One block per (b, h, 8 q-rows). Scores live in registers end-to-end.
__global__ __launch_bounds__(256, 4) void attn_kernel(
    const float* __restrict__ qw, const float* __restrict__ kw,
    const float* __restrict__ vw, float* __restrict__ out)
{
    __shared__ __align__(16) float vt[64][68];    // 17.4 KB v tile (+ reduce scratch)
    __shared__ __align__(16) float pls[ROWS][68]; //  2.2 KB p tile
    __shared__ __align__(16) float qT[DK][ROWS];  //  2.0 KB q transposed, pre-scaled 1/8
    __shared__ float wredA[4][ROWS], wredB[4][ROWS], wredC[4][ROWS];
    __shared__ float invls[ROWS];

    const int t    = threadIdx.x;
    const int lane = t & 63;
    const int w    = t >> 6;
    const int h    = blockIdx.y;
    const int b    = blockIdx.z;
    const size_t base = ((size_t)b * NH + h) * S * DK;
    const float* __restrict__ qp = qw + base;
    const float* __restrict__ kp = kw + base;   // kT layout: [DK][S]
    const float* __restrict__ vp = vw + base;
    const int q0 = blockIdx.x * ROWS;

    // ---- stage qT[d][r] = q[q0+r][d] / 8 ----
#pragma unroll
    for (int p = 0; p < 2; ++p) {
        int e = t + 256 * p;
        int d = e >> 3, r = e & 7;
        qT[d][r] = qp[(size_t)(q0 + r) * DK + d] * 0.125f;
    }
    __syncthreads();

    // ---- QK: thread owns keys 4t..4t+3; coalesced kT loads, 2-step ring ----
    float accf[ROWS][4] = {};          // scores, later p
    const float* __restrict__ kTb = kp + 4 * t;

    float4 kbuf[2][4];
#pragma unroll
    for (int d = 0; d < 4; ++d) kbuf[0][d] = *(const float4*)&kTb[(size_t)d * S];
#pragma unroll
    for (int d = 0; d < 4; ++d) kbuf[1][d] = *(const float4*)&kTb[(size_t)(4 + d) * S];

#pragma unroll
    for (int d0 = 0; d0 < DK; d0 += 4) {
        const int cur = (d0 >> 2) & 1;
        float4 kc[4] = {kbuf[cur][0], kbuf[cur][1], kbuf[cur][2], kbuf[cur][3]};
        if (d0 + 8 < DK) {
#pragma unroll
            for (int d = 0; d < 4; ++d)
                kbuf[cur][d] = *(const float4*)&kTb[(size_t)(d0 + 8 + d) * S];
        }
#pragma unroll
        for (int dd = 0; dd < 4; ++dd) {
            const int d = d0 + dd;
            float4 qa = *(const float4*)&qT[d][0];
            float4 qb = *(const float4*)&qT[d][4];
            float qr[8] = {qa.x, qa.y, qa.z, qa.w, qb.x, qb.y, qb.z, qb.w};
            float k4[4] = {kc[dd].x, kc[dd].y, kc[dd].z, kc[dd].w};
#pragma unroll
            for (int r = 0; r < ROWS; ++r)
#pragma unroll
                for (int i = 0; i < 4; ++i)
                    accf[r][i] += qr[r] * k4[i];
        }
    }

    // ---- row max (register partials -> wave -> block) ----
    float mx8[ROWS], zs8[ROWS];
#pragma unroll
    for (int r = 0; r < ROWS; ++r) {
        float pm = fmaxf(fmaxf(accf[r][0], accf[r][1]), fmaxf(accf[r][2], accf[r][3]));
        pm = wave_max(pm);
        if (lane == 0) wredA[w][r] = pm;
    }
    __syncthreads();
#pragma unroll
    for (int r = 0; r < ROWS; ++r)
        mx8[r] = fmaxf(fmaxf(wredA[0][r], wredA[1][r]), fmaxf(wredA[2][r], wredA[3][r]));

    // ---- zs (sharp partition sum) ----
#pragma unroll
    for (int r = 0; r < ROWS; ++r) {
        float pz = 0.f;
#pragma unroll
        for (int i = 0; i < 4; ++i)
            pz += __expf(100.f * (accf[r][i] - mx8[r]));
        pz = wave_sum(pz);
        if (lane == 0) wredB[w][r] = pz;
    }
    __syncthreads();
#pragma unroll
    for (int r = 0; r < ROWS; ++r)
        zs8[r] = ((wredB[0][r] + wredB[1][r]) + wredB[2][r]) + wredB[3][r];

    // ---- mask + final-softmax numerator in registers; z2 reduce ----
#pragma unroll
    for (int r = 0; r < ROWS; ++r) {
        const float zsr = zs8[r];
        const bool any  = !((1.0f / zsr) < THRESH);
        const float m2  = any ? mx8[r] : NEG_INF;
        float pz2 = 0.f;
#pragma unroll
        for (int i = 0; i < 4; ++i) {
            float x = accf[r][i];
            float e = __expf(100.f * (x - mx8[r]));
            bool keep = !((e / zsr) < THRESH);       // exactly the reference comparison
            float sp = keep ? x : NEG_INF;
            float p2 = __expf(sp - m2);              // all-masked row -> uniform
            accf[r][i] = p2;
            pz2 += p2;
        }
        pz2 = wave_sum(pz2);
        if (lane == 0) wredC[w][r] = pz2;
    }
    __syncthreads();
    if (t < ROWS) {
        float z2 = ((wredC[0][t] + wredC[1][t]) + wredC[2][t]) + wredC[3][t];
        invls[t] = 1.0f / z2;
    }

    // ---- PV: per 64-key tile, p round-trips through a 2.2 KB LDS tile ----
    const int dq  = t & 15;            // d = 4*dq
    const int ksp = (t >> 4) & 7;      // key split within tile
    const int rg  = t >> 7;            // rows 4rg..4rg+3
    float pacc[4][4] = {};

    for (int kt = 0; kt < 16; ++kt) {
        {   // stage v tile with XOR swizzle (kills the 4-way bank conflict)
            const int key = t >> 2, dsg = (t & 3) * 16, xr = 4 * ((key >> 3) & 3);
            const float* vr = vp + (size_t)(kt * 64 + key) * DK + dsg;
            float4 va = *(const float4*)(vr + 0);
            float4 vb = *(const float4*)(vr + 4);
            float4 vc = *(const float4*)(vr + 8);
            float4 vd = *(const float4*)(vr + 12);
            *(float4*)&vt[key][(dsg + 0) ^ xr]  = va;
            *(float4*)&vt[key][(dsg + 4) ^ xr]  = vb;
            *(float4*)&vt[key][(dsg + 8) ^ xr]  = vc;
            *(float4*)&vt[key][(dsg + 12) ^ xr] = vd;
        }
        if ((t >> 4) == kt) {          // this thread's keys live in this tile
            const int c4 = 4 * (t & 15);
#pragma unroll
            for (int r = 0; r < ROWS; ++r)
                *(float4*)&pls[r][c4] = make_float4(accf[r][0], accf[r][1], accf[r][2], accf[r][3]);
        }
        __syncthreads();
#pragma unroll
        for (int g = 0; g < 8; g += 4) {
            const int j0 = ksp * 8 + g;
            float4 at0 = *(const float4*)&pls[4 * rg + 0][j0];
            float4 at1 = *(const float4*)&pls[4 * rg + 1][j0];
            float4 at2 = *(const float4*)&pls[4 * rg + 2][j0];
            float4 at3 = *(const float4*)&pls[4 * rg + 3][j0];
            float ar[4][4] = {{at0.x, at0.y, at0.z, at0.w},
                              {at1.x, at1.y, at1.z, at1.w},
                              {at2.x, at2.y, at2.z, at2.w},
                              {at3.x, at3.y, at3.z, at3.w}};
#pragma unroll
            for (int kk = 0; kk < 4; ++kk) {
                float4 vv = *(const float4*)&vt[j0 + kk][(4 * dq) ^ (4 * (((j0 + kk) >> 3) & 3))];
                float v4[4] = {vv.x, vv.y, vv.z, vv.w};
#pragma unroll
                for (int i = 0; i < 4; ++i)
#pragma unroll
                    for (int jd = 0; jd < 4; ++jd)
                        pacc[i][jd] += ar[i][kk] * v4[jd];
            }
        }
        __syncthreads();
    }

    // ---- reduce 8-way key split (reuse vt), scale by 1/z2, write ----
    float* red = &vt[0][0];            // [ksp][r][64] = 16 KB
#pragma unroll
    for (int i = 0; i < 4; ++i)
        *(float4*)&red[ksp * 512 + (4 * rg + i) * 64 + 4 * dq] =
            make_float4(pacc[i][0], pacc[i][1], pacc[i][2], pacc[i][3]);
    __syncthreads();
#pragma unroll
    for (int p = 0; p < 2; ++p) {
        const int e = t + 256 * p;
        const int r = e >> 6, d = e & 63;
        float s = 0.f;
#pragma unroll
        for (int ks = 0; ks < 8; ++ks)
            s += red[ks * 512 + r * 64 + d];
        out[((size_t)b * S + q0 + r) * D + h * DK + d] = s * invls[r];
    }
}

extern "C" void kernel_launch(void* const* d_in, const int* in_sizes, int n_in,
                              void* d_out, int out_size, void* d_ws, size_t ws_size,
                              hipStream_t stream) {
    const float* Qi = (const float*)d_in[1];
    const float* Ki = (const float*)d_in[2];
    const float* Vi = (const float*)d_in[3];
    const float* Wq = (const float*)d_in[4];
    const float* bq = (const float*)d_in[5];
    const float* Wk = (const float*)d_in[6];
    const float* bk = (const float*)d_in[7];
    const float* Wv = (const float*)d_in[8];
    const float* bv = (const float*)d_in[9];
    float* outp = (float*)d_out;

    float* qws = (float*)d_ws;                       // [B,H,S,DK]
    float* kws = qws + (size_t)NB * NH * S * DK;     // [B,H,DK,S] (transposed)
    float* vws = kws + (size_t)NB * NH * S * DK;     // [B,H,S,DK]

    dim3 g1(D / 128, (NB * S) / 128, 3);
    proj_kernel<<<g1, 256, 0, stream>>>(Qi, Ki, Vi, Wq, bq, Wk, bk, Wv, bv, qws, kws, vws);

    dim3 g2(S / ROWS, NH, NB);
    attn_kernel<<<g2, 256, 0, stream>>>(qws, kws, vws, outp);
}

// Round 5
// 3301.278 us; speedup vs baseline: 2.1516x; 2.1516x over previous
//
#include <hip/hip_runtime.h>

constexpr int D = 1024;   // d_model
constexpr int S = 1024;   // seq len
constexpr int NB = 4;     // batch
constexpr int NH = 16;    // heads
constexpr int DK = 64;    // head dim
constexpr float THRESH = 0.019f;
constexpr float NEG_INF = -1e9f;
constexpr int ROWS = 8;   // q-rows per attention block

__device__ __forceinline__ float wave_max(float v) {
#pragma unroll
    for (int off = 32; off >= 1; off >>= 1)
        v = fmaxf(v, __shfl_xor(v, off, 64));
    return v;
}
__device__ __forceinline__ float wave_sum(float v) {
#pragma unroll
    for (int off = 32; off >= 1; off >>= 1)
        v += __shfl_xor(v, off, 64);
    return v;
}

// Y[m][n] = sum_k X[m][k] * W[n][k] + bias[n]. 128x128 tile, 8x8 micro-tile.
// q,v written head-split [B,H,S,DK]; k written TRANSPOSED [B,H,DK,S].
__global__ __launch_bounds__(256) void proj_kernel(
    const float* __restrict__ Qi, const float* __restrict__ Ki, const float* __restrict__ Vi,
    const float* __restrict__ Wq, const float* __restrict__ bq,
    const float* __restrict__ Wk, const float* __restrict__ bk,
    const float* __restrict__ Wv, const float* __restrict__ bv,
    float* __restrict__ qo, float* __restrict__ ko, float* __restrict__ vo)
{
    const int pz = blockIdx.z;
    const float* __restrict__ X    = (pz == 0) ? Qi : (pz == 1) ? Ki : Vi;
    const float* __restrict__ W    = (pz == 0) ? Wq : (pz == 1) ? Wk : Wv;
    const float* __restrict__ bias = (pz == 0) ? bq : (pz == 1) ? bk : bv;
    float* __restrict__ out        = (pz == 0) ? qo : (pz == 1) ? ko : vo;

    __shared__ __align__(16) float As[16][132];   // [k][m] transposed
    __shared__ __align__(16) float Bs[16][132];   // [k][n] transposed

    const int t  = threadIdx.x;
    const int tx = t & 15;
    const int ty = t >> 4;
    const int m0 = blockIdx.y * 128;
    const int n0 = blockIdx.x * 128;
    const int srow = t >> 1;           // staging row 0..127
    const int sk   = 8 * (t & 1);      // staging k offset 0 or 8

    float acc[2][2][4][4] = {};        // [im][in][i][j]

    for (int k0 = 0; k0 < D; k0 += 16) {
        float4 xa = *(const float4*)&X[(size_t)(m0 + srow) * D + k0 + sk];
        float4 xb = *(const float4*)&X[(size_t)(m0 + srow) * D + k0 + sk + 4];
        float4 wa = *(const float4*)&W[(size_t)(n0 + srow) * D + k0 + sk];
        float4 wb = *(const float4*)&W[(size_t)(n0 + srow) * D + k0 + sk + 4];
        As[sk + 0][srow] = xa.x; As[sk + 1][srow] = xa.y; As[sk + 2][srow] = xa.z; As[sk + 3][srow] = xa.w;
        As[sk + 4][srow] = xb.x; As[sk + 5][srow] = xb.y; As[sk + 6][srow] = xb.z; As[sk + 7][srow] = xb.w;
        Bs[sk + 0][srow] = wa.x; Bs[sk + 1][srow] = wa.y; Bs[sk + 2][srow] = wa.z; Bs[sk + 3][srow] = wa.w;
        Bs[sk + 4][srow] = wb.x; Bs[sk + 5][srow] = wb.y; Bs[sk + 6][srow] = wb.z; Bs[sk + 7][srow] = wb.w;
        __syncthreads();
#pragma unroll
        for (int kk = 0; kk < 16; ++kk) {
            float4 a0 = *(const float4*)&As[kk][ty * 4];
            float4 a1 = *(const float4*)&As[kk][ty * 4 + 64];
            float4 b0 = *(const float4*)&Bs[kk][tx * 4];
            float4 b1 = *(const float4*)&Bs[kk][tx * 4 + 64];
            float am[2][4] = {{a0.x, a0.y, a0.z, a0.w}, {a1.x, a1.y, a1.z, a1.w}};
            float bn[2][4] = {{b0.x, b0.y, b0.z, b0.w}, {b1.x, b1.y, b1.z, b1.w}};
#pragma unroll
            for (int im = 0; im < 2; ++im)
#pragma unroll
                for (int in = 0; in < 2; ++in)
#pragma unroll
                    for (int i = 0; i < 4; ++i)
#pragma unroll
                        for (int j = 0; j < 4; ++j)
                            acc[im][in][i][j] += am[im][i] * bn[in][j];
        }
        __syncthreads();
    }

    const int bb2 = m0 >> 10;              // batch (m0 multiple of 128)
    if (pz == 1) {
        // kT[((b*NH+h)*DK + d)*S + s], f4 along s
#pragma unroll
        for (int im = 0; im < 2; ++im) {
            const int s0 = (m0 & 1023) + ty * 4 + 64 * im;
#pragma unroll
            for (int in = 0; in < 2; ++in) {
#pragma unroll
                for (int j = 0; j < 4; ++j) {
                    const int n = n0 + tx * 4 + 64 * in + j;
                    const int h = n >> 6, d = n & 63;
                    const float bj = bias[n];
                    float4 wv = make_float4(acc[im][in][0][j] + bj, acc[im][in][1][j] + bj,
                                            acc[im][in][2][j] + bj, acc[im][in][3][j] + bj);
                    *(float4*)&out[(((size_t)bb2 * NH + h) * DK + d) * S + s0] = wv;
                }
            }
        }
    } else {
#pragma unroll
        for (int im = 0; im < 2; ++im)
#pragma unroll
            for (int i = 0; i < 4; ++i) {
                const int m  = m0 + ty * 4 + 64 * im + i;
                const int sr = m & 1023;
#pragma unroll
                for (int in = 0; in < 2; ++in) {
                    const int n = n0 + tx * 4 + 64 * in;
                    const int h = n >> 6, d = n & 63;
                    const float4 bj = *(const float4*)&bias[n];
                    float4 wv = make_float4(acc[im][in][i][0] + bj.x, acc[im][in][i][1] + bj.y,
                                            acc[im][in][i][2] + bj.z, acc[im][in][i][3] + bj.w);
                    *(float4*)&out[(((size_t)bb2 * NH + h) * S + sr) * DK + d] = wv;
                }
            }
    }
}

// One block per (b, h, 8 q-rows). Scores live in registers end-to-end.
// NOTE: plain __launch_bounds__(256). The (256,4) min-occupancy hint clamped
// the allocator to 64 VGPRs and spilled the score registers to scratch
// (19 GB HBM traffic, 9.3x slowdown). Let the allocator pick ~100-128.
__global__ __launch_bounds__(256) void attn_kernel(
    const float* __restrict__ qw, const float* __restrict__ kw,
    const float* __restrict__ vw, float* __restrict__ out)
{
    __shared__ __align__(16) float vt[64][68];    // 17.4 KB v tile (+ reduce scratch)
    __shared__ __align__(16) float pls[ROWS][68]; //  2.2 KB p tile
    __shared__ __align__(16) float qT[DK][ROWS];  //  2.0 KB q transposed, pre-scaled 1/8
    __shared__ float wredA[4][ROWS], wredB[4][ROWS], wredC[4][ROWS];
    __shared__ float invls[ROWS];

    const int t    = threadIdx.x;
    const int lane = t & 63;
    const int w    = t >> 6;
    const int h    = blockIdx.y;
    const int b    = blockIdx.z;
    const size_t base = ((size_t)b * NH + h) * S * DK;
    const float* __restrict__ qp = qw + base;
    const float* __restrict__ kp = kw + base;   // kT layout: [DK][S]
    const float* __restrict__ vp = vw + base;
    const int q0 = blockIdx.x * ROWS;

    // ---- stage qT[d][r] = q[q0+r][d] / 8 ----
#pragma unroll
    for (int p = 0; p < 2; ++p) {
        int e = t + 256 * p;
        int d = e >> 3, r = e & 7;
        qT[d][r] = qp[(size_t)(q0 + r) * DK + d] * 0.125f;
    }
    __syncthreads();

    // ---- QK: thread owns keys 4t..4t+3; coalesced kT loads, 2-step ring ----
    float accf[ROWS][4] = {};          // scores, later p
    const float* __restrict__ kTb = kp + 4 * t;

    float4 kbuf[2][4];
#pragma unroll
    for (int d = 0; d < 4; ++d) kbuf[0][d] = *(const float4*)&kTb[(size_t)d * S];
#pragma unroll
    for (int d = 0; d < 4; ++d) kbuf[1][d] = *(const float4*)&kTb[(size_t)(4 + d) * S];

#pragma unroll
    for (int d0 = 0; d0 < DK; d0 += 4) {
        const int cur = (d0 >> 2) & 1;
        float4 kc[4] = {kbuf[cur][0], kbuf[cur][1], kbuf[cur][2], kbuf[cur][3]};
        if (d0 + 8 < DK) {
#pragma unroll
            for (int d = 0; d < 4; ++d)
                kbuf[cur][d] = *(const float4*)&kTb[(size_t)(d0 + 8 + d) * S];
        }
#pragma unroll
        for (int dd = 0; dd < 4; ++dd) {
            const int d = d0 + dd;
            float4 qa = *(const float4*)&qT[d][0];
            float4 qb = *(const float4*)&qT[d][4];
            float qr[8] = {qa.x, qa.y, qa.z, qa.w, qb.x, qb.y, qb.z, qb.w};
            float k4[4] = {kc[dd].x, kc[dd].y, kc[dd].z, kc[dd].w};
#pragma unroll
            for (int r = 0; r < ROWS; ++r)
#pragma unroll
                for (int i = 0; i < 4; ++i)
                    accf[r][i] += qr[r] * k4[i];
        }
    }

    // ---- row max (register partials -> wave -> block) ----
    float mx8[ROWS], zs8[ROWS];
#pragma unroll
    for (int r = 0; r < ROWS; ++r) {
        float pm = fmaxf(fmaxf(accf[r][0], accf[r][1]), fmaxf(accf[r][2], accf[r][3]));
        pm = wave_max(pm);
        if (lane == 0) wredA[w][r] = pm;
    }
    __syncthreads();
#pragma unroll
    for (int r = 0; r < ROWS; ++r)
        mx8[r] = fmaxf(fmaxf(wredA[0][r], wredA[1][r]), fmaxf(wredA[2][r], wredA[3][r]));

    // ---- zs (sharp partition sum) ----
#pragma unroll
    for (int r = 0; r < ROWS; ++r) {
        float pz = 0.f;
#pragma unroll
        for (int i = 0; i < 4; ++i)
            pz += __expf(100.f * (accf[r][i] - mx8[r]));
        pz = wave_sum(pz);
        if (lane == 0) wredB[w][r] = pz;
    }
    __syncthreads();
#pragma unroll
    for (int r = 0; r < ROWS; ++r)
        zs8[r] = ((wredB[0][r] + wredB[1][r]) + wredB[2][r]) + wredB[3][r];

    // ---- mask + final-softmax numerator in registers; z2 reduce ----
#pragma unroll
    for (int r = 0; r < ROWS; ++r) {
        const float zsr = zs8[r];
        const bool any  = !((1.0f / zsr) < THRESH);
        const float m2  = any ? mx8[r] : NEG_INF;
        float pz2 = 0.f;
#pragma unroll
        for (int i = 0; i < 4; ++i) {
            float x = accf[r][i];
            float e = __expf(100.f * (x - mx8[r]));
            bool keep = !((e / zsr) < THRESH);       // exactly the reference comparison
            float sp = keep ? x : NEG_INF;
            float p2 = __expf(sp - m2);              // all-masked row -> uniform
            accf[r][i] = p2;
            pz2 += p2;
        }
        pz2 = wave_sum(pz2);
        if (lane == 0) wredC[w][r] = pz2;
    }
    __syncthreads();
    if (t < ROWS) {
        float z2 = ((wredC[0][t] + wredC[1][t]) + wredC[2][t]) + wredC[3][t];
        invls[t] = 1.0f / z2;
    }

    // ---- PV: per 64-key tile, p round-trips through a 2.2 KB LDS tile ----
    const int dq  = t & 15;            // d = 4*dq
    const int ksp = (t >> 4) & 7;      // key split within tile
    const int rg  = t >> 7;            // rows 4rg..4rg+3
    float pacc[4][4] = {};

    for (int kt = 0; kt < 16; ++kt) {
        {   // stage v tile with XOR swizzle (kills the 4-way bank conflict)
            const int key = t >> 2, dsg = (t & 3) * 16, xr = 4 * ((key >> 3) & 3);
            const float* vr = vp + (size_t)(kt * 64 + key) * DK + dsg;
            float4 va = *(const float4*)(vr + 0);
            float4 vb = *(const float4*)(vr + 4);
            float4 vc = *(const float4*)(vr + 8);
            float4 vd = *(const float4*)(vr + 12);
            *(float4*)&vt[key][(dsg + 0) ^ xr]  = va;
            *(float4*)&vt[key][(dsg + 4) ^ xr]  = vb;
            *(float4*)&vt[key][(dsg + 8) ^ xr]  = vc;
            *(float4*)&vt[key][(dsg + 12) ^ xr] = vd;
        }
        if ((t >> 4) == kt) {          // this thread's keys live in this tile
            const int c4 = 4 * (t & 15);
#pragma unroll
            for (int r = 0; r < ROWS; ++r)
                *(float4*)&pls[r][c4] = make_float4(accf[r][0], accf[r][1], accf[r][2], accf[r][3]);
        }
        __syncthreads();
#pragma unroll
        for (int g = 0; g < 8; g += 4) {
            const int j0 = ksp * 8 + g;
            float4 at0 = *(const float4*)&pls[4 * rg + 0][j0];
            float4 at1 = *(const float4*)&pls[4 * rg + 1][j0];
            float4 at2 = *(const float4*)&pls[4 * rg + 2][j0];
            float4 at3 = *(const float4*)&pls[4 * rg + 3][j0];
            float ar[4][4] = {{at0.x, at0.y, at0.z, at0.w},
                              {at1.x, at1.y, at1.z, at1.w},
                              {at2.x, at2.y, at2.z, at2.w},
                              {at3.x, at3.y, at3.z, at3.w}};
#pragma unroll
            for (int kk = 0; kk < 4; ++kk) {
                float4 vv = *(const float4*)&vt[j0 + kk][(4 * dq) ^ (4 * (((j0 + kk) >> 3) & 3))];
                float v4[4] = {vv.x, vv.y, vv.z, vv.w};
#pragma unroll
                for (int i = 0; i < 4; ++i)
#pragma unroll
                    for (int jd = 0; jd < 4; ++jd)
                        pacc[i][jd] += ar[i][kk] * v4[jd];
            }
        }
        __syncthreads();
    }

    // ---- reduce 8-way key split (reuse vt), scale by 1/z2, write ----
    float* red = &vt[0][0];            // [ksp][r][64] = 16 KB
#pragma unroll
    for (int i = 0; i < 4; ++i)
        *(float4*)&red[ksp * 512 + (4 * rg + i) * 64 + 4 * dq] =
            make_float4(pacc[i][0], pacc[i][1], pacc[i][2], pacc[i][3]);
    __syncthreads();
#pragma unroll
    for (int p = 0; p < 2; ++p) {
        const int e = t + 256 * p;
        const int r = e >> 6, d = e & 63;
        float s = 0.f;
#pragma unroll
        for (int ks = 0; ks < 8; ++ks)
            s += red[ks * 512 + r * 64 + d];
        out[((size_t)b * S + q0 + r) * D + h * DK + d] = s * invls[r];
    }
}

extern "C" void kernel_launch(void* const* d_in, const int* in_sizes, int n_in,
                              void* d_out, int out_size, void* d_ws, size_t ws_size,
                              hipStream_t stream) {
    const float* Qi = (const float*)d_in[1];
    const float* Ki = (const float*)d_in[2];
    const float* Vi = (const float*)d_in[3];
    const float* Wq = (const float*)d_in[4];
    const float* bq = (const float*)d_in[5];
    const float* Wk = (const float*)d_in[6];
    const float* bk = (const float*)d_in[7];
    const float* Wv = (const float*)d_in[8];
    const float* bv = (const float*)d_in[9];
    float* outp = (float*)d_out;

    float* qws = (float*)d_ws;                       // [B,H,S,DK]
    float* kws = qws + (size_t)NB * NH * S * DK;     // [B,H,DK,S] (transposed)
    float* vws = kws + (size_t)NB * NH * S * DK;     // [B,H,S,DK]

    dim3 g1(D / 128, (NB * S) / 128, 3);
    proj_kernel<<<g1, 256, 0, stream>>>(Qi, Ki, Vi, Wq, bq, Wk, bk, Wv, bv, qws, kws, vws);

    dim3 g2(S / ROWS, NH, NB);
    attn_kernel<<<g2, 256, 0, stream>>>(qws, kws, vws, outp);
}

// Round 6
// 3287.702 us; speedup vs baseline: 2.1605x; 1.0041x over previous
//
#include <hip/hip_runtime.h>

constexpr int D = 1024;   // d_model
constexpr int S = 1024;   // seq len
constexpr int NB = 4;     // batch
constexpr int NH = 16;    // heads
constexpr int DK = 64;    // head dim
constexpr float THRESH = 0.019f;
constexpr float NEG_INF = -1e9f;
constexpr int ROWS = 8;   // q-rows per attention block

__device__ __forceinline__ float wave_max(float v) {
#pragma unroll
    for (int off = 32; off >= 1; off >>= 1)
        v = fmaxf(v, __shfl_xor(v, off, 64));
    return v;
}
__device__ __forceinline__ float wave_sum(float v) {
#pragma unroll
    for (int off = 32; off >= 1; off >>= 1)
        v += __shfl_xor(v, off, 64);
    return v;
}

// Y[m][n] = sum_k X[m][k] * W[n][k] + bias[n]. 128x128 tile, 8x8 micro-tile.
// q,v written head-split [B,H,S,DK]; k written TRANSPOSED [B,H,DK,S].
__global__ __launch_bounds__(256) void proj_kernel(
    const float* __restrict__ Qi, const float* __restrict__ Ki, const float* __restrict__ Vi,
    const float* __restrict__ Wq, const float* __restrict__ bq,
    const float* __restrict__ Wk, const float* __restrict__ bk,
    const float* __restrict__ Wv, const float* __restrict__ bv,
    float* __restrict__ qo, float* __restrict__ ko, float* __restrict__ vo)
{
    const int pz = blockIdx.z;
    const float* __restrict__ X    = (pz == 0) ? Qi : (pz == 1) ? Ki : Vi;
    const float* __restrict__ W    = (pz == 0) ? Wq : (pz == 1) ? Wk : Wv;
    const float* __restrict__ bias = (pz == 0) ? bq : (pz == 1) ? bk : bv;
    float* __restrict__ out        = (pz == 0) ? qo : (pz == 1) ? ko : vo;

    __shared__ __align__(16) float As[16][132];   // [k][m] transposed
    __shared__ __align__(16) float Bs[16][132];   // [k][n] transposed

    const int t  = threadIdx.x;
    const int tx = t & 15;
    const int ty = t >> 4;
    const int m0 = blockIdx.y * 128;
    const int n0 = blockIdx.x * 128;
    const int srow = t >> 1;           // staging row 0..127
    const int sk   = 8 * (t & 1);      // staging k offset 0 or 8

    float acc[2][2][4][4] = {};        // [im][in][i][j]

    for (int k0 = 0; k0 < D; k0 += 16) {
        float4 xa = *(const float4*)&X[(size_t)(m0 + srow) * D + k0 + sk];
        float4 xb = *(const float4*)&X[(size_t)(m0 + srow) * D + k0 + sk + 4];
        float4 wa = *(const float4*)&W[(size_t)(n0 + srow) * D + k0 + sk];
        float4 wb = *(const float4*)&W[(size_t)(n0 + srow) * D + k0 + sk + 4];
        As[sk + 0][srow] = xa.x; As[sk + 1][srow] = xa.y; As[sk + 2][srow] = xa.z; As[sk + 3][srow] = xa.w;
        As[sk + 4][srow] = xb.x; As[sk + 5][srow] = xb.y; As[sk + 6][srow] = xb.z; As[sk + 7][srow] = xb.w;
        Bs[sk + 0][srow] = wa.x; Bs[sk + 1][srow] = wa.y; Bs[sk + 2][srow] = wa.z; Bs[sk + 3][srow] = wa.w;
        Bs[sk + 4][srow] = wb.x; Bs[sk + 5][srow] = wb.y; Bs[sk + 6][srow] = wb.z; Bs[sk + 7][srow] = wb.w;
        __syncthreads();
#pragma unroll
        for (int kk = 0; kk < 16; ++kk) {
            float4 a0 = *(const float4*)&As[kk][ty * 4];
            float4 a1 = *(const float4*)&As[kk][ty * 4 + 64];
            float4 b0 = *(const float4*)&Bs[kk][tx * 4];
            float4 b1 = *(const float4*)&Bs[kk][tx * 4 + 64];
            float am[2][4] = {{a0.x, a0.y, a0.z, a0.w}, {a1.x, a1.y, a1.z, a1.w}};
            float bn[2][4] = {{b0.x, b0.y, b0.z, b0.w}, {b1.x, b1.y, b1.z, b1.w}};
#pragma unroll
            for (int im = 0; im < 2; ++im)
#pragma unroll
                for (int in = 0; in < 2; ++in)
#pragma unroll
                    for (int i = 0; i < 4; ++i)
#pragma unroll
                        for (int j = 0; j < 4; ++j)
                            acc[im][in][i][j] += am[im][i] * bn[in][j];
        }
        __syncthreads();
    }

    const int bb2 = m0 >> 10;              // batch (m0 multiple of 128)
    if (pz == 1) {
        // kT[((b*NH+h)*DK + d)*S + s], f4 along s
#pragma unroll
        for (int im = 0; im < 2; ++im) {
            const int s0 = (m0 & 1023) + ty * 4 + 64 * im;
#pragma unroll
            for (int in = 0; in < 2; ++in) {
#pragma unroll
                for (int j = 0; j < 4; ++j) {
                    const int n = n0 + tx * 4 + 64 * in + j;
                    const int h = n >> 6, d = n & 63;
                    const float bj = bias[n];
                    float4 wv = make_float4(acc[im][in][0][j] + bj, acc[im][in][1][j] + bj,
                                            acc[im][in][2][j] + bj, acc[im][in][3][j] + bj);
                    *(float4*)&out[(((size_t)bb2 * NH + h) * DK + d) * S + s0] = wv;
                }
            }
        }
    } else {
#pragma unroll
        for (int im = 0; im < 2; ++im)
#pragma unroll
            for (int i = 0; i < 4; ++i) {
                const int m  = m0 + ty * 4 + 64 * im + i;
                const int sr = m & 1023;
#pragma unroll
                for (int in = 0; in < 2; ++in) {
                    const int n = n0 + tx * 4 + 64 * in;
                    const int h = n >> 6, d = n & 63;
                    const float4 bj = *(const float4*)&bias[n];
                    float4 wv = make_float4(acc[im][in][i][0] + bj.x, acc[im][in][i][1] + bj.y,
                                            acc[im][in][i][2] + bj.z, acc[im][in][i][3] + bj.w);
                    *(float4*)&out[(((size_t)bb2 * NH + h) * S + sr) * DK + d] = wv;
                }
            }
    }
}

// One block per (b, h, 8 q-rows). Scores live in registers end-to-end.
// #pragma unroll 1 on the PV loop is load-bearing: full unroll made the
// compiler hoist 16 iterations of v-staging loads -> 256 VGPRs + scratch
// spills (2.2 GB writes, 6x slowdown in R4/R5).
__global__ __launch_bounds__(256) void attn_kernel(
    const float* __restrict__ qw, const float* __restrict__ kw,
    const float* __restrict__ vw, float* __restrict__ out)
{
    __shared__ __align__(16) float vt[64][68];    // 17.4 KB v tile (+ reduce scratch)
    __shared__ __align__(16) float pls[ROWS][68]; //  2.2 KB p tile
    __shared__ __align__(16) float qT[DK][ROWS];  //  2.0 KB q transposed, pre-scaled 1/8
    __shared__ float wredA[4][ROWS], wredB[4][ROWS], wredC[4][ROWS];
    __shared__ float invls[ROWS];

    const int t    = threadIdx.x;
    const int lane = t & 63;
    const int w    = t >> 6;
    const int h    = blockIdx.y;
    const int b    = blockIdx.z;
    const size_t base = ((size_t)b * NH + h) * S * DK;
    const float* __restrict__ qp = qw + base;
    const float* __restrict__ kp = kw + base;   // kT layout: [DK][S]
    const float* __restrict__ vp = vw + base;
    const int q0 = blockIdx.x * ROWS;

    // ---- stage qT[d][r] = q[q0+r][d] / 8 ----
#pragma unroll
    for (int p = 0; p < 2; ++p) {
        int e = t + 256 * p;
        int d = e >> 3, r = e & 7;
        qT[d][r] = qp[(size_t)(q0 + r) * DK + d] * 0.125f;
    }
    __syncthreads();

    // ---- QK: thread owns keys 4t..4t+3; coalesced kT loads, 2-step ring ----
    float accf[ROWS][4] = {};          // scores, later p
    const float* __restrict__ kTb = kp + 4 * t;

    float4 kbuf[2][4];
#pragma unroll
    for (int d = 0; d < 4; ++d) kbuf[0][d] = *(const float4*)&kTb[(size_t)d * S];
#pragma unroll
    for (int d = 0; d < 4; ++d) kbuf[1][d] = *(const float4*)&kTb[(size_t)(4 + d) * S];

#pragma unroll
    for (int d0 = 0; d0 < DK; d0 += 4) {
        const int cur = (d0 >> 2) & 1;
        float4 kc[4] = {kbuf[cur][0], kbuf[cur][1], kbuf[cur][2], kbuf[cur][3]};
        if (d0 + 8 < DK) {
#pragma unroll
            for (int d = 0; d < 4; ++d)
                kbuf[cur][d] = *(const float4*)&kTb[(size_t)(d0 + 8 + d) * S];
        }
#pragma unroll
        for (int dd = 0; dd < 4; ++dd) {
            const int d = d0 + dd;
            float4 qa = *(const float4*)&qT[d][0];
            float4 qb = *(const float4*)&qT[d][4];
            float qr[8] = {qa.x, qa.y, qa.z, qa.w, qb.x, qb.y, qb.z, qb.w};
            float k4[4] = {kc[dd].x, kc[dd].y, kc[dd].z, kc[dd].w};
#pragma unroll
            for (int r = 0; r < ROWS; ++r)
#pragma unroll
                for (int i = 0; i < 4; ++i)
                    accf[r][i] += qr[r] * k4[i];
        }
    }

    // ---- row max (register partials -> wave -> block) ----
    float mx8[ROWS], zs8[ROWS];
#pragma unroll
    for (int r = 0; r < ROWS; ++r) {
        float pm = fmaxf(fmaxf(accf[r][0], accf[r][1]), fmaxf(accf[r][2], accf[r][3]));
        pm = wave_max(pm);
        if (lane == 0) wredA[w][r] = pm;
    }
    __syncthreads();
#pragma unroll
    for (int r = 0; r < ROWS; ++r)
        mx8[r] = fmaxf(fmaxf(wredA[0][r], wredA[1][r]), fmaxf(wredA[2][r], wredA[3][r]));

    // ---- zs (sharp partition sum) ----
#pragma unroll
    for (int r = 0; r < ROWS; ++r) {
        float pz = 0.f;
#pragma unroll
        for (int i = 0; i < 4; ++i)
            pz += __expf(100.f * (accf[r][i] - mx8[r]));
        pz = wave_sum(pz);
        if (lane == 0) wredB[w][r] = pz;
    }
    __syncthreads();
#pragma unroll
    for (int r = 0; r < ROWS; ++r)
        zs8[r] = ((wredB[0][r] + wredB[1][r]) + wredB[2][r]) + wredB[3][r];

    // ---- mask + final-softmax numerator in registers; z2 reduce ----
#pragma unroll
    for (int r = 0; r < ROWS; ++r) {
        const float zsr = zs8[r];
        const bool any  = !((1.0f / zsr) < THRESH);
        const float m2  = any ? mx8[r] : NEG_INF;
        float pz2 = 0.f;
#pragma unroll
        for (int i = 0; i < 4; ++i) {
            float x = accf[r][i];
            float e = __expf(100.f * (x - mx8[r]));
            bool keep = !((e / zsr) < THRESH);       // exactly the reference comparison
            float sp = keep ? x : NEG_INF;
            float p2 = __expf(sp - m2);              // all-masked row -> uniform
            accf[r][i] = p2;
            pz2 += p2;
        }
        pz2 = wave_sum(pz2);
        if (lane == 0) wredC[w][r] = pz2;
    }
    __syncthreads();
    if (t < ROWS) {
        float z2 = ((wredC[0][t] + wredC[1][t]) + wredC[2][t]) + wredC[3][t];
        invls[t] = 1.0f / z2;
    }
    __syncthreads();   // invls is read by pls staging in the PV loop

    // ---- PV: per 64-key tile, p round-trips through a 2.2 KB LDS tile ----
    // vt rows are rotated by 4*(key>>3) floats so the 4 ksp-groups (rows 8
    // apart; 8*68*4B = 544B = 0 mod 128B) hit distinct banks.
    const int dq  = t & 15;            // d = 4*dq
    const int ksp = (t >> 4) & 7;      // key split within tile
    const int rg  = t >> 7;            // rows 4rg..4rg+3
    float pacc[4][4] = {};

#pragma unroll 1
    for (int kt = 0; kt < 16; ++kt) {
        {   // stage v tile, per-row rotation
            const int key = t >> 2, dsg = (t & 3) * 16, rot = 4 * (key >> 3);
            const float* vr = vp + (size_t)(kt * 64 + key) * DK + dsg;
            float4 va = *(const float4*)(vr + 0);
            float4 vb = *(const float4*)(vr + 4);
            float4 vc = *(const float4*)(vr + 8);
            float4 vd = *(const float4*)(vr + 12);
            *(float4*)&vt[key][(dsg + 0 + rot) & 63]  = va;
            *(float4*)&vt[key][(dsg + 4 + rot) & 63]  = vb;
            *(float4*)&vt[key][(dsg + 8 + rot) & 63]  = vc;
            *(float4*)&vt[key][(dsg + 12 + rot) & 63] = vd;
        }
        if ((t >> 4) == kt) {          // this thread's keys live in this tile
            const int c4 = 4 * (t & 15);
#pragma unroll
            for (int r = 0; r < ROWS; ++r) {
                const float iv = invls[r];
                *(float4*)&pls[r][c4] = make_float4(accf[r][0] * iv, accf[r][1] * iv,
                                                    accf[r][2] * iv, accf[r][3] * iv);
            }
        }
        __syncthreads();
#pragma unroll
        for (int g = 0; g < 8; g += 4) {
            const int j0 = ksp * 8 + g;
            float4 at0 = *(const float4*)&pls[4 * rg + 0][j0];
            float4 at1 = *(const float4*)&pls[4 * rg + 1][j0];
            float4 at2 = *(const float4*)&pls[4 * rg + 2][j0];
            float4 at3 = *(const float4*)&pls[4 * rg + 3][j0];
            float ar[4][4] = {{at0.x, at0.y, at0.z, at0.w},
                              {at1.x, at1.y, at1.z, at1.w},
                              {at2.x, at2.y, at2.z, at2.w},
                              {at3.x, at3.y, at3.z, at3.w}};
#pragma unroll
            for (int kk = 0; kk < 4; ++kk) {
                const int key = j0 + kk;
                float4 vv = *(const float4*)&vt[key][(4 * dq + 4 * (key >> 3)) & 63];
                float v4[4] = {vv.x, vv.y, vv.z, vv.w};
#pragma unroll
                for (int i = 0; i < 4; ++i)
#pragma unroll
                    for (int jd = 0; jd < 4; ++jd)
                        pacc[i][jd] += ar[i][kk] * v4[jd];
            }
        }
        __syncthreads();
    }

    // ---- reduce 8-way key split (reuse vt), write (1/z2 already applied) ----
    float* red = &vt[0][0];            // [ksp][r][64] = 16 KB
#pragma unroll
    for (int i = 0; i < 4; ++i)
        *(float4*)&red[ksp * 512 + (4 * rg + i) * 64 + 4 * dq] =
            make_float4(pacc[i][0], pacc[i][1], pacc[i][2], pacc[i][3]);
    __syncthreads();
#pragma unroll
    for (int p = 0; p < 2; ++p) {
        const int e = t + 256 * p;
        const int r = e >> 6, d = e & 63;
        float s = 0.f;
#pragma unroll
        for (int ks = 0; ks < 8; ++ks)
            s += red[ks * 512 + r * 64 + d];
        out[((size_t)b * S + q0 + r) * D + h * DK + d] = s;
    }
}

extern "C" void kernel_launch(void* const* d_in, const int* in_sizes, int n_in,
                              void* d_out, int out_size, void* d_ws, size_t ws_size,
                              hipStream_t stream) {
    const float* Qi = (const float*)d_in[1];
    const float* Ki = (const float*)d_in[2];
    const float* Vi = (const float*)d_in[3];
    const float* Wq = (const float*)d_in[4];
    const float* bq = (const float*)d_in[5];
    const float* Wk = (const float*)d_in[6];
    const float* bk = (const float*)d_in[7];
    const float* Wv = (const float*)d_in[8];
    const float* bv = (const float*)d_in[9];
    float* outp = (float*)d_out;

    float* qws = (float*)d_ws;                       // [B,H,S,DK]
    float* kws = qws + (size_t)NB * NH * S * DK;     // [B,H,DK,S] (transposed)
    float* vws = kws + (size_t)NB * NH * S * DK;     // [B,H,S,DK]

    dim3 g1(D / 128, (NB * S) / 128, 3);
    proj_kernel<<<g1, 256, 0, stream>>>(Qi, Ki, Vi, Wq, bq, Wk, bk, Wv, bv, qws, kws, vws);

    dim3 g2(S / ROWS, NH, NB);
    attn_kernel<<<g2, 256, 0, stream>>>(qws, kws, vws, outp);
}

// Round 7
// 849.389 us; speedup vs baseline: 8.3625x; 3.8707x over previous
//
#include <hip/hip_runtime.h>

constexpr int D = 1024;   // d_model
constexpr int S = 1024;   // seq len
constexpr int NB = 4;     // batch
constexpr int NH = 16;    // heads
constexpr int DK = 64;    // head dim
constexpr float THRESH = 0.019f;
constexpr float NEG_INF = -1e9f;
constexpr int ROWS = 8;   // q-rows per attention block

__device__ __forceinline__ float wave_max(float v) {
#pragma unroll
    for (int off = 32; off >= 1; off >>= 1)
        v = fmaxf(v, __shfl_xor(v, off, 64));
    return v;
}
__device__ __forceinline__ float wave_sum(float v) {
#pragma unroll
    for (int off = 32; off >= 1; off >>= 1)
        v += __shfl_xor(v, off, 64);
    return v;
}

// Y[m][n] = sum_k X[m][k] * W[n][k] + bias[n]. 128x128 tile, 8x8 micro-tile.
// q,v written head-split [B,H,S,DK]; k written TRANSPOSED [B,H,DK,S].
__global__ __launch_bounds__(256) void proj_kernel(
    const float* __restrict__ Qi, const float* __restrict__ Ki, const float* __restrict__ Vi,
    const float* __restrict__ Wq, const float* __restrict__ bq,
    const float* __restrict__ Wk, const float* __restrict__ bk,
    const float* __restrict__ Wv, const float* __restrict__ bv,
    float* __restrict__ qo, float* __restrict__ ko, float* __restrict__ vo)
{
    const int pz = blockIdx.z;
    const float* __restrict__ X    = (pz == 0) ? Qi : (pz == 1) ? Ki : Vi;
    const float* __restrict__ W    = (pz == 0) ? Wq : (pz == 1) ? Wk : Wv;
    const float* __restrict__ bias = (pz == 0) ? bq : (pz == 1) ? bk : bv;
    float* __restrict__ out        = (pz == 0) ? qo : (pz == 1) ? ko : vo;

    __shared__ __align__(16) float As[16][132];   // [k][m] transposed
    __shared__ __align__(16) float Bs[16][132];   // [k][n] transposed

    const int t  = threadIdx.x;
    const int tx = t & 15;
    const int ty = t >> 4;
    const int m0 = blockIdx.y * 128;
    const int n0 = blockIdx.x * 128;
    const int srow = t >> 1;           // staging row 0..127
    const int sk   = 8 * (t & 1);      // staging k offset 0 or 8

    float acc[2][2][4][4] = {};        // [im][in][i][j]

    for (int k0 = 0; k0 < D; k0 += 16) {
        float4 xa = *(const float4*)&X[(size_t)(m0 + srow) * D + k0 + sk];
        float4 xb = *(const float4*)&X[(size_t)(m0 + srow) * D + k0 + sk + 4];
        float4 wa = *(const float4*)&W[(size_t)(n0 + srow) * D + k0 + sk];
        float4 wb = *(const float4*)&W[(size_t)(n0 + srow) * D + k0 + sk + 4];
        As[sk + 0][srow] = xa.x; As[sk + 1][srow] = xa.y; As[sk + 2][srow] = xa.z; As[sk + 3][srow] = xa.w;
        As[sk + 4][srow] = xb.x; As[sk + 5][srow] = xb.y; As[sk + 6][srow] = xb.z; As[sk + 7][srow] = xb.w;
        Bs[sk + 0][srow] = wa.x; Bs[sk + 1][srow] = wa.y; Bs[sk + 2][srow] = wa.z; Bs[sk + 3][srow] = wa.w;
        Bs[sk + 4][srow] = wb.x; Bs[sk + 5][srow] = wb.y; Bs[sk + 6][srow] = wb.z; Bs[sk + 7][srow] = wb.w;
        __syncthreads();
#pragma unroll
        for (int kk = 0; kk < 16; ++kk) {
            float4 a0 = *(const float4*)&As[kk][ty * 4];
            float4 a1 = *(const float4*)&As[kk][ty * 4 + 64];
            float4 b0 = *(const float4*)&Bs[kk][tx * 4];
            float4 b1 = *(const float4*)&Bs[kk][tx * 4 + 64];
            float am[2][4] = {{a0.x, a0.y, a0.z, a0.w}, {a1.x, a1.y, a1.z, a1.w}};
            float bn[2][4] = {{b0.x, b0.y, b0.z, b0.w}, {b1.x, b1.y, b1.z, b1.w}};
#pragma unroll
            for (int im = 0; im < 2; ++im)
#pragma unroll
                for (int in = 0; in < 2; ++in)
#pragma unroll
                    for (int i = 0; i < 4; ++i)
#pragma unroll
                        for (int j = 0; j < 4; ++j)
                            acc[im][in][i][j] += am[im][i] * bn[in][j];
        }
        __syncthreads();
    }

    const int bb2 = m0 >> 10;              // batch (m0 multiple of 128)
    if (pz == 1) {
        // kT[((b*NH+h)*DK + d)*S + s], f4 along s
#pragma unroll
        for (int im = 0; im < 2; ++im) {
            const int s0 = (m0 & 1023) + ty * 4 + 64 * im;
#pragma unroll
            for (int in = 0; in < 2; ++in) {
#pragma unroll
                for (int j = 0; j < 4; ++j) {
                    const int n = n0 + tx * 4 + 64 * in + j;
                    const int h = n >> 6, d = n & 63;
                    const float bj = bias[n];
                    float4 wv = make_float4(acc[im][in][0][j] + bj, acc[im][in][1][j] + bj,
                                            acc[im][in][2][j] + bj, acc[im][in][3][j] + bj);
                    *(float4*)&out[(((size_t)bb2 * NH + h) * DK + d) * S + s0] = wv;
                }
            }
        }
    } else {
#pragma unroll
        for (int im = 0; im < 2; ++im)
#pragma unroll
            for (int i = 0; i < 4; ++i) {
                const int m  = m0 + ty * 4 + 64 * im + i;
                const int sr = m & 1023;
#pragma unroll
                for (int in = 0; in < 2; ++in) {
                    const int n = n0 + tx * 4 + 64 * in;
                    const int h = n >> 6, d = n & 63;
                    const float4 bj = *(const float4*)&bias[n];
                    float4 wv = make_float4(acc[im][in][i][0] + bj.x, acc[im][in][i][1] + bj.y,
                                            acc[im][in][i][2] + bj.z, acc[im][in][i][3] + bj.w);
                    *(float4*)&out[(((size_t)bb2 * NH + h) * S + sr) * DK + d] = wv;
                }
            }
    }
}

// One block per (b, h, 8 q-rows). Register QK + register softmax; the
// normalized p is written ONCE to LDS (pss) so accf dies before the PV loop
// (R5/R6 kept accf live across the whole PV loop -> 256 VGPRs + scratch
// spills re-loaded every iteration, ~0.5 MB/block of HBM scratch traffic).
__global__ __launch_bounds__(256) void attn_kernel(
    const float* __restrict__ qw, const float* __restrict__ kw,
    const float* __restrict__ vw, float* __restrict__ out)
{
    __shared__ __align__(16) float pss[ROWS][S];  // 32 KB normalized p
    __shared__ __align__(16) float vt[64][68];    // 17.4 KB v tile (+ reduce scratch)
    __shared__ __align__(16) float qT[DK][ROWS];  //  2.0 KB q transposed, pre-scaled 1/8
    __shared__ float wredA[4][ROWS], wredB[4][ROWS], wredC[4][ROWS];
    __shared__ float invls[ROWS];

    const int t    = threadIdx.x;
    const int lane = t & 63;
    const int w    = t >> 6;
    const int h    = blockIdx.y;
    const int b    = blockIdx.z;
    const size_t base = ((size_t)b * NH + h) * S * DK;
    const float* __restrict__ qp = qw + base;
    const float* __restrict__ kp = kw + base;   // kT layout: [DK][S]
    const float* __restrict__ vp = vw + base;
    const int q0 = blockIdx.x * ROWS;

    // ---- stage qT[d][r] = q[q0+r][d] / 8 ----
#pragma unroll
    for (int p = 0; p < 2; ++p) {
        int e = t + 256 * p;
        int d = e >> 3, r = e & 7;
        qT[d][r] = qp[(size_t)(q0 + r) * DK + d] * 0.125f;
    }
    __syncthreads();

    // ---- QK: thread owns keys 4t..4t+3; coalesced kT loads, 2-step ring.
    // unroll 2: keeps `cur` static and bounds in-flight k-loads to 8 float4s
    // (full unroll lets the compiler hoist up to 64 loads = 256 VGPRs).
    float accf[ROWS][4] = {};          // scores, later p
    const float* __restrict__ kTb = kp + 4 * t;

    float4 kbuf[2][4];
#pragma unroll
    for (int d = 0; d < 4; ++d) kbuf[0][d] = *(const float4*)&kTb[(size_t)d * S];
#pragma unroll
    for (int d = 0; d < 4; ++d) kbuf[1][d] = *(const float4*)&kTb[(size_t)(4 + d) * S];

#pragma unroll 2
    for (int d0 = 0; d0 < DK; d0 += 4) {
        const int cur = (d0 >> 2) & 1;
        float4 kc[4] = {kbuf[cur][0], kbuf[cur][1], kbuf[cur][2], kbuf[cur][3]};
        if (d0 + 8 < DK) {
#pragma unroll
            for (int d = 0; d < 4; ++d)
                kbuf[cur][d] = *(const float4*)&kTb[(size_t)(d0 + 8 + d) * S];
        }
#pragma unroll
        for (int dd = 0; dd < 4; ++dd) {
            const int d = d0 + dd;
            float4 qa = *(const float4*)&qT[d][0];
            float4 qb = *(const float4*)&qT[d][4];
            float qr[8] = {qa.x, qa.y, qa.z, qa.w, qb.x, qb.y, qb.z, qb.w};
            float k4[4] = {kc[dd].x, kc[dd].y, kc[dd].z, kc[dd].w};
#pragma unroll
            for (int r = 0; r < ROWS; ++r)
#pragma unroll
                for (int i = 0; i < 4; ++i)
                    accf[r][i] += qr[r] * k4[i];
        }
    }

    // ---- row max (register partials -> wave -> block) ----
    float mx8[ROWS], zs8[ROWS];
#pragma unroll
    for (int r = 0; r < ROWS; ++r) {
        float pm = fmaxf(fmaxf(accf[r][0], accf[r][1]), fmaxf(accf[r][2], accf[r][3]));
        pm = wave_max(pm);
        if (lane == 0) wredA[w][r] = pm;
    }
    __syncthreads();
#pragma unroll
    for (int r = 0; r < ROWS; ++r)
        mx8[r] = fmaxf(fmaxf(wredA[0][r], wredA[1][r]), fmaxf(wredA[2][r], wredA[3][r]));

    // ---- zs (sharp partition sum) ----
#pragma unroll
    for (int r = 0; r < ROWS; ++r) {
        float pz = 0.f;
#pragma unroll
        for (int i = 0; i < 4; ++i)
            pz += __expf(100.f * (accf[r][i] - mx8[r]));
        pz = wave_sum(pz);
        if (lane == 0) wredB[w][r] = pz;
    }
    __syncthreads();
#pragma unroll
    for (int r = 0; r < ROWS; ++r)
        zs8[r] = ((wredB[0][r] + wredB[1][r]) + wredB[2][r]) + wredB[3][r];

    // ---- mask + final-softmax numerator in registers; z2 reduce ----
#pragma unroll
    for (int r = 0; r < ROWS; ++r) {
        const float zsr = zs8[r];
        const bool any  = !((1.0f / zsr) < THRESH);
        const float m2  = any ? mx8[r] : NEG_INF;
        float pz2 = 0.f;
#pragma unroll
        for (int i = 0; i < 4; ++i) {
            float x = accf[r][i];
            float e = __expf(100.f * (x - mx8[r]));
            bool keep = !((e / zsr) < THRESH);       // exactly the reference comparison
            float sp = keep ? x : NEG_INF;
            float p2 = __expf(sp - m2);              // all-masked row -> uniform
            accf[r][i] = p2;
            pz2 += p2;
        }
        pz2 = wave_sum(pz2);
        if (lane == 0) wredC[w][r] = pz2;
    }
    __syncthreads();
    if (t < ROWS) {
        float z2 = ((wredC[0][t] + wredC[1][t]) + wredC[2][t]) + wredC[3][t];
        invls[t] = 1.0f / z2;
    }
    __syncthreads();

    // ---- write normalized p to LDS once; accf dead after this ----
#pragma unroll
    for (int r = 0; r < ROWS; ++r) {
        const float iv = invls[r];
        *(float4*)&pss[r][4 * t] = make_float4(accf[r][0] * iv, accf[r][1] * iv,
                                               accf[r][2] * iv, accf[r][3] * iv);
    }
    __syncthreads();

    // ---- PV: thread = (rg: 4 rows, ksp: key split, dq: 4 d-cols) ----
    // vt rows rotated by 4*(key>>3) floats: rows 8 apart (544 B = 0 mod 128)
    // land on distinct bank quads. p reads are 4-address b128 broadcasts.
    const int dq  = t & 15;            // d = 4*dq
    const int ksp = (t >> 4) & 7;      // key split within tile
    const int rg  = t >> 7;            // rows 4rg..4rg+3
    float pacc[4][4] = {};

#pragma unroll 1
    for (int kt = 0; kt < 16; ++kt) {
        {   // stage v tile, per-row rotation
            const int key = t >> 2, dsg = (t & 3) * 16, rot = 4 * (key >> 3);
            const float* vr = vp + (size_t)(kt * 64 + key) * DK + dsg;
            float4 va = *(const float4*)(vr + 0);
            float4 vb = *(const float4*)(vr + 4);
            float4 vc = *(const float4*)(vr + 8);
            float4 vd = *(const float4*)(vr + 12);
            *(float4*)&vt[key][(dsg + 0 + rot) & 63]  = va;
            *(float4*)&vt[key][(dsg + 4 + rot) & 63]  = vb;
            *(float4*)&vt[key][(dsg + 8 + rot) & 63]  = vc;
            *(float4*)&vt[key][(dsg + 12 + rot) & 63] = vd;
        }
        __syncthreads();
#pragma unroll
        for (int g = 0; g < 8; g += 4) {
            const int j0 = ksp * 8 + g;
            float4 at0 = *(const float4*)&pss[4 * rg + 0][kt * 64 + j0];
            float4 at1 = *(const float4*)&pss[4 * rg + 1][kt * 64 + j0];
            float4 at2 = *(const float4*)&pss[4 * rg + 2][kt * 64 + j0];
            float4 at3 = *(const float4*)&pss[4 * rg + 3][kt * 64 + j0];
            float ar[4][4] = {{at0.x, at0.y, at0.z, at0.w},
                              {at1.x, at1.y, at1.z, at1.w},
                              {at2.x, at2.y, at2.z, at2.w},
                              {at3.x, at3.y, at3.z, at3.w}};
#pragma unroll
            for (int kk = 0; kk < 4; ++kk) {
                const int key = j0 + kk;
                float4 vv = *(const float4*)&vt[key][(4 * dq + 4 * (key >> 3)) & 63];
                float v4[4] = {vv.x, vv.y, vv.z, vv.w};
#pragma unroll
                for (int i = 0; i < 4; ++i)
#pragma unroll
                    for (int jd = 0; jd < 4; ++jd)
                        pacc[i][jd] += ar[i][kk] * v4[jd];
            }
        }
        __syncthreads();
    }

    // ---- reduce 8-way key split (reuse vt), write (1/z2 already applied) ----
    float* red = &vt[0][0];            // [ksp][r][64] = 16 KB
#pragma unroll
    for (int i = 0; i < 4; ++i)
        *(float4*)&red[ksp * 512 + (4 * rg + i) * 64 + 4 * dq] =
            make_float4(pacc[i][0], pacc[i][1], pacc[i][2], pacc[i][3]);
    __syncthreads();
#pragma unroll
    for (int p = 0; p < 2; ++p) {
        const int e = t + 256 * p;
        const int r = e >> 6, d = e & 63;
        float s = 0.f;
#pragma unroll
        for (int ks = 0; ks < 8; ++ks)
            s += red[ks * 512 + r * 64 + d];
        out[((size_t)b * S + q0 + r) * D + h * DK + d] = s;
    }
}

extern "C" void kernel_launch(void* const* d_in, const int* in_sizes, int n_in,
                              void* d_out, int out_size, void* d_ws, size_t ws_size,
                              hipStream_t stream) {
    const float* Qi = (const float*)d_in[1];
    const float* Ki = (const float*)d_in[2];
    const float* Vi = (const float*)d_in[3];
    const float* Wq = (const float*)d_in[4];
    const float* bq = (const float*)d_in[5];
    const float* Wk = (const float*)d_in[6];
    const float* bk = (const float*)d_in[7];
    const float* Wv = (const float*)d_in[8];
    const float* bv = (const float*)d_in[9];
    float* outp = (float*)d_out;

    float* qws = (float*)d_ws;                       // [B,H,S,DK]
    float* kws = qws + (size_t)NB * NH * S * DK;     // [B,H,DK,S] (transposed)
    float* vws = kws + (size_t)NB * NH * S * DK;     // [B,H,S,DK]

    dim3 g1(D / 128, (NB * S) / 128, 3);
    proj_kernel<<<g1, 256, 0, stream>>>(Qi, Ki, Vi, Wq, bq, Wk, bk, Wv, bv, qws, kws, vws);

    dim3 g2(S / ROWS, NH, NB);
    attn_kernel<<<g2, 256, 0, stream>>>(qws, kws, vws, outp);
}